// Round 2
// baseline (308.497 us; speedup 1.0000x reference)
//
#include <hip/hip_runtime.h>
#include <hip/hip_bf16.h>

#define BB 8
#define NN 8192
#define MM 2048
#define C1 64
#define C2 128
#define CIN 192
#define CO 128
#define NB (BB*NN)
#define EPS 1e-5f

typedef unsigned short u16;
typedef unsigned int u32;
typedef unsigned long long u64;

static __device__ __forceinline__ float b2f(u16 u) {
    return __uint_as_float(((u32)u) << 16);
}
static __device__ __forceinline__ u16 f2b(float f) {
    __hip_bfloat16 h = __float2bfloat16(f);
    u16 u;
    __builtin_memcpy(&u, &h, 2);
    return u;
}
// dtype-adaptive input load: bf=1 -> bf16, bf=0 -> f32
static __device__ __forceinline__ float ldin(const void* p, int i, int bf) {
    if (bf) return b2f(((const u16*)p)[i]);
    return ((const float*)p)[i];
}

// ---------------- dtype detector: bf16 vs f32 ----------------
__global__ void k_detect(const void* probe, int* flag) {
    int t = threadIdx.x;  // 64 threads
    u16 u = ((const u16*)probe)[t * 7 + 1];
    int e = (u >> 7) & 0xff;
    int sane = ((u & 0x7fff) == 0) || (e >= 100 && e <= 130);
    u64 m = __ballot(sane);
    if (t == 0) flag[0] = (__popcll(m) >= 56) ? 1 : 0;
}

// ---------------- weight transpose + f32 upconvert ----------------
__global__ void k_prep_w(const void* W0, const void* W1,
                         float* __restrict__ W0T, float* __restrict__ W1T,
                         const int* __restrict__ flag) {
    int bfm = flag[0];
    int t = blockIdx.x * 256 + threadIdx.x;
    if (t < CIN * CO) {
        int o = t / CIN, i = t - o * CIN;      // W0 is [CO][CIN]
        W0T[i * CO + o] = ldin(W0, t, bfm);
    }
    if (t < 128 * 128) {
        int o = t >> 7, i = t & 127;           // W1 is [128][128]
        W1T[i * 128 + o] = ldin(W1, t, bfm);
    }
}

// ---------------- high_feats transpose: [B][C2][M] -> [B][M][C2] (bf16) ----------------
__global__ void k_prep_h(const void* hf, u16* __restrict__ hT, const int* __restrict__ flag) {
    __shared__ u16 s[64][65];
    int bfm = flag[0];
    int b = blockIdx.x, m0 = blockIdx.y * 64, c0 = blockIdx.z * 64;
    for (int e = threadIdx.x; e < 64 * 64; e += 256) {
        int i = e >> 6, j = e & 63;            // i: c, j: m  (coalesced in m)
        s[i][j] = f2b(ldin(hf, (b * C2 + c0 + i) * MM + m0 + j, bfm));
    }
    __syncthreads();
    for (int e = threadIdx.x; e < 64 * 64; e += 256) {
        int ii = e & 63, jj = e >> 6;          // coalesced in c
        hT[(b * MM + m0 + jj) * C2 + c0 + ii] = s[ii][jj];
    }
}

// ---------------- nearest neighbor (match np f32 semantics exactly) ----------------
__global__ void k_argmin(const void* lt_, const void* lp_,
                         const void* ht_, const void* hp_,
                         int* __restrict__ idx, const int* __restrict__ flag) {
    __shared__ float2 hs[MM];
    int bfm = flag[0];
    int b = blockIdx.x >> 5;                    // 32 blocks per batch
    int n = ((blockIdx.x & 31) << 8) + threadIdx.x;
    for (int m = threadIdx.x; m < MM; m += 256) {
        hs[m] = make_float2(ldin(ht_, b * MM + m, bfm), ldin(hp_, b * MM + m, bfm));
    }
    __syncthreads();
    float lt = ldin(lt_, b * NN + n, bfm);
    float lp = ldin(lp_, b * NN + n, bfm);
    float bestd2 = 1e30f, bestd = 1e30f;
    int bi = 0;
    for (int m = 0; m < MM; ++m) {
        float2 h = hs[m];
        float dt = lt - h.x;
        float dp = lp - h.y;
        // no-FMA exact f32: matches numpy mul,mul,add
        float d2 = __fadd_rn(__fmul_rn(dt, dt), __fmul_rn(dp, dp));
        if (d2 < bestd2) {                      // monotone filter (sqrt order-preserving)
            float d = __fsqrt_rn(d2);           // ref argmins over f32 sqrt
            if (d < bestd) { bestd = d; bi = m; }  // strict < : first index wins
            bestd2 = d2;
        }
    }
    idx[b * NN + n] = bi;
}

// ---------------- layer 0: gather + concat + GEMM + partial BN stats ----------------
// y0 (bf16) goes to d_out (bf16 mode) or ws scratch (f32 mode); selected on device.
__global__ __launch_bounds__(256) void k_gemm0(
        const void* lf, const u16* __restrict__ hT,
        const int* __restrict__ idx, const float* __restrict__ WT,
        const void* bias, u16* __restrict__ y0a, u16* __restrict__ y0b,
        float* __restrict__ gsum, float* __restrict__ gsq,
        const int* __restrict__ flag) {
    __shared__ float xs[CIN][68];
    __shared__ float chs[CO], chq[CO];
    __shared__ int idxs[64];
    int bfm = flag[0];
    u16* __restrict__ y0 = bfm ? y0a : y0b;
    int b = blockIdx.x >> 7;                    // 128 n-tiles per batch
    int n0 = (blockIdx.x & 127) << 6;
    int tid = threadIdx.x;
    if (tid < 64) idxs[tid] = idx[b * NN + n0 + tid];
    if (tid < CO) { chs[tid] = 0.f; chq[tid] = 0.f; }
    __syncthreads();
    // low feats rows 0..63 (coalesced in n)
    for (int e = tid; e < C1 * 64; e += 256) {
        int c = e >> 6, n = e & 63;
        xs[c][n] = ldin(lf, (b * C1 + c) * NN + n0 + n, bfm);
    }
    // gathered high feats rows 64..191 (contiguous per column from hT)
    for (int e = tid; e < C2 * 64; e += 256) {
        int n = e >> 7, c = e & 127;
        xs[C1 + c][n] = b2f(hT[(b * MM + idxs[n]) * C2 + c]);
    }
    __syncthreads();

    int col0 = (tid & 15) << 2;
    int row0 = (tid >> 4) << 3;
    float acc[8][4];
#pragma unroll
    for (int r = 0; r < 8; ++r)
#pragma unroll
        for (int c = 0; c < 4; ++c) acc[r][c] = 0.f;

    for (int i = 0; i < CIN; ++i) {
        float4 x = *(const float4*)&xs[i][col0];
        const float4* wp = (const float4*)(WT + i * CO + row0);
        float4 wa = wp[0], wb = wp[1];
        float w[8] = {wa.x, wa.y, wa.z, wa.w, wb.x, wb.y, wb.z, wb.w};
#pragma unroll
        for (int r = 0; r < 8; ++r) {
            acc[r][0] += w[r] * x.x;
            acc[r][1] += w[r] * x.y;
            acc[r][2] += w[r] * x.z;
            acc[r][3] += w[r] * x.w;
        }
    }

#pragma unroll
    for (int r = 0; r < 8; ++r) {
        float bs = ldin(bias, row0 + r, bfm);
        float y[4], s = 0.f, q = 0.f;
        u32 pack[2];
#pragma unroll
        for (int c = 0; c < 4; ++c) {
            y[c] = acc[r][c] + bs;
            s += y[c];
            q += y[c] * y[c];
        }
        pack[0] = (u32)f2b(y[0]) | ((u32)f2b(y[1]) << 16);
        pack[1] = (u32)f2b(y[2]) | ((u32)f2b(y[3]) << 16);
        *(uint2*)(y0 + ((b * CO + row0 + r) * NN + n0 + col0)) =
            make_uint2(pack[0], pack[1]);
        atomicAdd(&chs[row0 + r], s);
        atomicAdd(&chq[row0 + r], q);
    }
    __syncthreads();
    if (tid < CO) atomicAdd(&gsum[tid], chs[tid]);
    else if (tid < 2 * CO) atomicAdd(&gsq[tid - CO], chq[tid - CO]);
}

// ---------------- BN finalize ----------------
__global__ void k_finalize(const float* __restrict__ gsum, const float* __restrict__ gsq,
                           float* __restrict__ mean, float* __restrict__ istd) {
    int c = threadIdx.x;
    float mu = gsum[c] * (1.f / NB);
    float var = gsq[c] * (1.f / NB) - mu * mu;
    mean[c] = mu;
    istd[c] = 1.f / __fsqrt_rn(var + EPS);
}

// ---------------- layer 1: normalize(y0)+ReLU -> GEMM + partial BN stats ----------------
// reads its own y0 tile, writes y1 over the same tile region of d_out (in-place safe).
__global__ __launch_bounds__(256) void k_gemm1(
        u16* __restrict__ y0a, u16* __restrict__ y0b,
        const float* __restrict__ mean0, const float* __restrict__ istd0,
        const void* g0, const void* be0,
        const float* __restrict__ WT, const void* bias,
        void* __restrict__ dout, float* __restrict__ gsum, float* __restrict__ gsq,
        const int* __restrict__ flag) {
    __shared__ float xs[CO][68];
    __shared__ float chs[CO], chq[CO];
    int bfm = flag[0];
    const u16* __restrict__ y0 = bfm ? y0a : y0b;
    int b = blockIdx.x >> 7;
    int n0 = (blockIdx.x & 127) << 6;
    int tid = threadIdx.x;
    if (tid < CO) { chs[tid] = 0.f; chq[tid] = 0.f; }
    __syncthreads();
    for (int e = tid; e < CO * 64; e += 256) {
        int c = e >> 6, n = e & 63;
        float v = b2f(y0[(b * CO + c) * NN + n0 + n]);
        float hcv = ldin(g0, c, bfm) * ((v - mean0[c]) * istd0[c]) + ldin(be0, c, bfm);
        xs[c][n] = fmaxf(hcv, 0.f);
    }
    __syncthreads();

    int col0 = (tid & 15) << 2;
    int row0 = (tid >> 4) << 3;
    float acc[8][4];
#pragma unroll
    for (int r = 0; r < 8; ++r)
#pragma unroll
        for (int c = 0; c < 4; ++c) acc[r][c] = 0.f;

    for (int i = 0; i < CO; ++i) {
        float4 x = *(const float4*)&xs[i][col0];
        const float4* wp = (const float4*)(WT + i * CO + row0);
        float4 wa = wp[0], wb = wp[1];
        float w[8] = {wa.x, wa.y, wa.z, wa.w, wb.x, wb.y, wb.z, wb.w};
#pragma unroll
        for (int r = 0; r < 8; ++r) {
            acc[r][0] += w[r] * x.x;
            acc[r][1] += w[r] * x.y;
            acc[r][2] += w[r] * x.z;
            acc[r][3] += w[r] * x.w;
        }
    }

#pragma unroll
    for (int r = 0; r < 8; ++r) {
        float bs = ldin(bias, row0 + r, bfm);
        float y[4], s = 0.f, q = 0.f;
#pragma unroll
        for (int c = 0; c < 4; ++c) {
            y[c] = acc[r][c] + bs;
            s += y[c];
            q += y[c] * y[c];
        }
        int base = (b * CO + row0 + r) * NN + n0 + col0;
        if (bfm) {
            u32 p0 = (u32)f2b(y[0]) | ((u32)f2b(y[1]) << 16);
            u32 p1 = (u32)f2b(y[2]) | ((u32)f2b(y[3]) << 16);
            *(uint2*)((u16*)dout + base) = make_uint2(p0, p1);
        } else {
            *(float4*)((float*)dout + base) = make_float4(y[0], y[1], y[2], y[3]);
        }
        atomicAdd(&chs[row0 + r], s);
        atomicAdd(&chq[row0 + r], q);
    }
    __syncthreads();
    if (tid < CO) atomicAdd(&gsum[tid], chs[tid]);
    else if (tid < 2 * CO) atomicAdd(&gsq[tid - CO], chq[tid - CO]);
}

// ---------------- final normalize in-place on d_out ----------------
__global__ void k_final(void* __restrict__ dout,
                        const float* __restrict__ mean, const float* __restrict__ istd,
                        const void* g, const void* beta, const int* __restrict__ flag) {
    int bfm = flag[0];
    int t = blockIdx.x * 256 + threadIdx.x;
    int e0 = t << 3;
    int o = (e0 >> 13) & 127;
    float mu = mean[o], is = istd[o];
    float gg = ldin(g, o, bfm), bb = ldin(beta, o, bfm);
    if (bfm) {
        u16* y1 = (u16*)dout;
        uint4 v = *(const uint4*)(y1 + e0);
        u32 vv[4] = {v.x, v.y, v.z, v.w};
        u32 rr[4];
#pragma unroll
        for (int k = 0; k < 4; ++k) {
            float lo = b2f((u16)(vv[k] & 0xffffu));
            float hi = b2f((u16)(vv[k] >> 16));
            lo = fmaxf(gg * ((lo - mu) * is) + bb, 0.f);
            hi = fmaxf(gg * ((hi - mu) * is) + bb, 0.f);
            rr[k] = (u32)f2b(lo) | ((u32)f2b(hi) << 16);
        }
        *(uint4*)(y1 + e0) = make_uint4(rr[0], rr[1], rr[2], rr[3]);
    } else {
        float* y1 = (float*)dout;
        float4 a = *(const float4*)(y1 + e0);
        float4 bq = *(const float4*)(y1 + e0 + 4);
        float vv[8] = {a.x, a.y, a.z, a.w, bq.x, bq.y, bq.z, bq.w};
#pragma unroll
        for (int k = 0; k < 8; ++k)
            vv[k] = fmaxf(gg * ((vv[k] - mu) * is) + bb, 0.f);
        *(float4*)(y1 + e0) = make_float4(vv[0], vv[1], vv[2], vv[3]);
        *(float4*)(y1 + e0 + 4) = make_float4(vv[4], vv[5], vv[6], vv[7]);
    }
}

extern "C" void kernel_launch(void* const* d_in, const int* in_sizes, int n_in,
                              void* d_out, int out_size, void* d_ws, size_t ws_size,
                              hipStream_t stream) {
    const void* lt = d_in[0];
    const void* lp = d_in[1];
    const void* lf = d_in[2];
    const void* ht = d_in[3];
    const void* hp = d_in[4];
    const void* hf = d_in[5];
    const void* W0 = d_in[6];
    const void* b0 = d_in[7];
    const void* g0 = d_in[8];
    const void* be0 = d_in[9];
    const void* W1 = d_in[10];
    const void* b1 = d_in[11];
    const void* g1 = d_in[12];
    const void* be1 = d_in[13];

    char* ws = (char*)d_ws;
    int* idx = (int*)(ws + 0);                       // 256KB
    float* gs0 = (float*)(ws + 262144);              // 4x128 f32 accumulators
    float* gq0 = gs0 + 128;
    float* gs1 = gq0 + 128;
    float* gq1 = gs1 + 128;
    float* mean0 = (float*)(ws + 264192);
    float* istd0 = mean0 + 128;
    float* mean1 = istd0 + 128;
    float* istd1 = mean1 + 128;
    int* flag = (int*)(ws + 266240);
    float* W0T = (float*)(ws + 266304);              // 98KB
    float* W1T = (float*)(ws + 364608);              // 64KB
    u16* hT = (u16*)(ws + 430144);                   // 4.19MB
    u16* y0ws = (u16*)(ws + 4624448);                // only touched in f32-input mode

    hipMemsetAsync(gs0, 0, 4 * 128 * sizeof(float), stream);
    k_detect<<<1, 64, 0, stream>>>(lf, flag);
    k_prep_w<<<96, 256, 0, stream>>>(W0, W1, W0T, W1T, flag);
    k_prep_h<<<dim3(8, 32, 2), 256, 0, stream>>>(hf, hT, flag);
    k_argmin<<<256, 256, 0, stream>>>(lt, lp, ht, hp, idx, flag);
    k_gemm0<<<1024, 256, 0, stream>>>(lf, hT, idx, W0T, b0,
                                      (u16*)d_out, y0ws, gs0, gq0, flag);
    k_finalize<<<1, 128, 0, stream>>>(gs0, gq0, mean0, istd0);
    k_gemm1<<<1024, 256, 0, stream>>>((u16*)d_out, y0ws, mean0, istd0, g0, be0,
                                      W1T, b1, d_out, gs1, gq1, flag);
    k_finalize<<<1, 128, 0, stream>>>(gs1, gq1, mean1, istd1);
    k_final<<<4096, 256, 0, stream>>>(d_out, mean1, istd1, g1, be1, flag);
}

// Round 5
// 167.248 us; speedup vs baseline: 1.8445x; 1.8445x over previous
//
#include <hip/hip_runtime.h>
#include <hip/hip_bf16.h>

#define BB 8
#define NN 8192
#define MM 2048
#define C1 64
#define C2 128
#define CIN 192
#define CO 128
#define NB (BB*NN)
#define EPS 1e-5f

typedef unsigned short u16;
typedef unsigned int u32;
typedef __bf16 bf16_t;
typedef bf16_t bf16x8 __attribute__((ext_vector_type(8)));
typedef float f32x4 __attribute__((ext_vector_type(4)));

static __device__ __forceinline__ float b2f(u16 u) { return __uint_as_float(((u32)u) << 16); }
static __device__ __forceinline__ u16 f2b(float f) {
    __hip_bfloat16 h = __float2bfloat16(f);
    u16 u; __builtin_memcpy(&u, &h, 2); return u;
}

// ---------------- weights f32 -> bf16 (same layout) ----------------
__global__ void k_prep_w(const float* __restrict__ W0, const float* __restrict__ W1,
                         u16* __restrict__ W0b, u16* __restrict__ W1b) {
    int t = blockIdx.x * 256 + threadIdx.x;      // 96 blocks = 24576 threads
    if (t < CIN * CO) W0b[t] = f2b(W0[t]);
    if (t < CO * CO)  W1b[t] = f2b(W1[t]);
}

// ---------------- high_feats transpose: f32 [B][C2][M] -> bf16 [B][M][C2] ----------------
__global__ void k_prep_h(const float* __restrict__ hf, u16* __restrict__ hT) {
    __shared__ u16 s[64][65];
    int b = blockIdx.x, m0 = blockIdx.y * 64, c0 = blockIdx.z * 64;
    for (int e = threadIdx.x; e < 64 * 64; e += 256) {
        int i = e >> 6, j = e & 63;                 // i: c, j: m (coalesced in m)
        s[i][j] = f2b(hf[(b * C2 + c0 + i) * MM + m0 + j]);
    }
    __syncthreads();
    for (int e = threadIdx.x; e < 64 * 64; e += 256) {
        int ii = e & 63, jj = e >> 6;               // coalesced in c
        hT[(b * MM + m0 + jj) * C2 + c0 + ii] = s[ii][jj];
    }
}

// ---------------- nearest neighbor (np f32 semantics, bitwise) ----------------
// lazy sqrt on monotone-filter hits; strict < (first index wins) over f32 sqrt
// exactly like np.argmin over sqrt(dt^2+dp^2); d2 via rn mul,mul,add (no FMA).
__global__ __launch_bounds__(256) void k_argmin(
        const float* __restrict__ lt_, const float* __restrict__ lp_,
        const float* __restrict__ ht_, const float* __restrict__ hp_,
        int* __restrict__ idx) {
    __shared__ float2 hs[4 * 516];                  // per-part offset kills bank aliasing
    int b = blockIdx.x >> 7;
    int n0 = (blockIdx.x & 127) << 6;
    int tid = threadIdx.x;
    for (int e = tid; e < MM; e += 256) {
        int p = e >> 9, i = e & 511;
        hs[p * 516 + i] = make_float2(ht_[b * MM + e], hp_[b * MM + e]);
    }
    __syncthreads();
    int q = tid >> 2, p = tid & 3;                  // 64 queries x 4 m-parts per block
    float lt = lt_[b * NN + n0 + q];
    float lp = lp_[b * NN + n0 + q];
    float bestd[4] = {1e30f, 1e30f, 1e30f, 1e30f};  // over sqrt values
    float bestd2[4] = {1e30f, 1e30f, 1e30f, 1e30f}; // monotone filter
    int bi[4] = {0, 0, 0, 0};
    const float2* hp2 = &hs[p * 516];
    int mbase = p << 9;
    for (int i = 0; i < 512; i += 4) {
#pragma unroll
        for (int c = 0; c < 4; ++c) {               // 4 independent chains for ILP
            float2 h = hp2[i + c];
            float dt = lt - h.x, dp = lp - h.y;
            float d2 = __fadd_rn(__fmul_rn(dt, dt), __fmul_rn(dp, dp)); // no-FMA = np
            if (d2 < bestd2[c]) {
                float d = __fsqrt_rn(d2);           // rare (≈log m times per chain)
                if (d < bestd[c]) { bestd[c] = d; bi[c] = mbase + i + c; }
                bestd2[c] = d2;
            }
        }
    }
    float bv = bestd[0]; int bm = bi[0];
#pragma unroll
    for (int c = 1; c < 4; ++c)
        if (bestd[c] < bv || (bestd[c] == bv && bi[c] < bm)) { bv = bestd[c]; bm = bi[c]; }
#pragma unroll
    for (int d = 1; d <= 2; d <<= 1) {              // merge 4 parts (lanes 4q+p)
        float ov = __shfl_xor(bv, d, 64);
        int om = __shfl_xor(bm, d, 64);
        if (ov < bv || (ov == bv && om < bm)) { bv = ov; bm = om; }
    }
    if (p == 0) idx[b * NN + n0 + q] = bm;
}

// epilogue: bias add, per-channel sum/sumsq (f32, pre-rounding), bf16 store to ylds[o][n swz]
static __device__ __forceinline__ void epilogue(
        f32x4* ac0, f32x4* ac1, const float* bias, u16* yl,
        float* chs, float* chq, int w, int ln, int q) {
#pragma unroll
    for (int mf = 0; mf < 2; ++mf) {
        f32x4* A = mf ? ac1 : ac0;
        int chb = 32 * w + 16 * mf + 4 * q;
        float bs[4], ss[4] = {0.f, 0.f, 0.f, 0.f}, sq[4] = {0.f, 0.f, 0.f, 0.f};
#pragma unroll
        for (int r = 0; r < 4; ++r) bs[r] = bias[chb + r];
#pragma unroll
        for (int nf = 0; nf < 4; ++nf) {
            int n = (nf << 4) + ln;
#pragma unroll
            for (int r = 0; r < 4; ++r) {
                float y = A[nf][r] + bs[r];
                ss[r] += y; sq[r] += y * y;
                int o = chb + r;
                yl[(o << 6) + (n ^ ((o & 7) << 3))] = f2b(y);
            }
        }
#pragma unroll
        for (int r = 0; r < 4; ++r) {
            float v = ss[r], u2 = sq[r];
#pragma unroll
            for (int d = 1; d < 16; d <<= 1) {
                v += __shfl_xor(v, d, 64);
                u2 += __shfl_xor(u2, d, 64);
            }
            if (ln == 0) { atomicAdd(&chs[chb + r], v); atomicAdd(&chq[chb + r], u2); }
        }
    }
}

// ---------------- layer 0: gather + MFMA gemm + bias -> y0 (ws, bf16) + stats0 ----------------
__global__ __launch_bounds__(256) void k_l0(
        const float* __restrict__ lf, const u16* __restrict__ hT, const int* __restrict__ idx,
        const u16* __restrict__ W0b, const float* __restrict__ b0,
        u16* __restrict__ y0, float* __restrict__ gstat) {
    __shared__ u16 xt[64 * CIN];          // B-tile [n][k] XOR-chunk-swizzled (24.5KB)
    __shared__ u16 ylds[CO * 64];         // y tile [o][n swz] (16KB)
    __shared__ float chs[CO], chq[CO];
    __shared__ int idxs[64];
    int tid = threadIdx.x;
    int l = tid & 63, w = tid >> 6, ln = l & 15, q = l >> 4;
    int b = blockIdx.x >> 7, n0 = (blockIdx.x & 127) << 6;
    if (tid < 64) idxs[tid] = idx[b * NN + n0 + tid];
    if (tid < 128) { chs[tid] = 0.f; chq[tid] = 0.f; }
    __syncthreads();
    // stage low_feats rows 0..63 via in-register transpose (lane = channel, f32 -> bf16)
    {
        const float* src = lf + (size_t)(b * C1 + l) * NN + n0 + (w << 4);
        float4 f0 = *(const float4*)src;
        float4 f1 = *(const float4*)(src + 4);
        float4 f2 = *(const float4*)(src + 8);
        float4 f3 = *(const float4*)(src + 12);
        float v[16] = {f0.x, f0.y, f0.z, f0.w, f1.x, f1.y, f1.z, f1.w,
                       f2.x, f2.y, f2.z, f2.w, f3.x, f3.y, f3.z, f3.w};
        int cc = l >> 3, clo = l & 7;
#pragma unroll
        for (int i = 0; i < 16; ++i) {
            int n = (w << 4) + i;
            xt[n * CIN + ((cc ^ (i & 7)) << 3) + clo] = f2b(v[i]);
        }
    }
    // gather nearest high rows (contiguous 256B per row from bf16 hT)
    for (int e = tid; e < 1024; e += 256) {
        int n = e >> 4, c16 = e & 15;
        uint4 v = *(const uint4*)(hT + (size_t)(b * MM + idxs[n]) * C2 + (c16 << 3));
        *(uint4*)&xt[n * CIN + (((8 + c16) ^ (n & 7)) << 3)] = v;
    }
    __syncthreads();
    f32x4 ac0[4], ac1[4];
#pragma unroll
    for (int nf = 0; nf < 4; ++nf) {
        ac0[nf] = f32x4{0.f, 0.f, 0.f, 0.f};
        ac1[nf] = f32x4{0.f, 0.f, 0.f, 0.f};
    }
    const u16* w0r0 = W0b + (32 * w + ln) * CIN + 8 * q;
    const u16* w0r1 = w0r0 + 16 * CIN;
#pragma unroll
    for (int s = 0; s < 6; ++s) {
        bf16x8 a0 = *(const bf16x8*)(w0r0 + 32 * s);
        bf16x8 a1 = *(const bf16x8*)(w0r1 + 32 * s);
#pragma unroll
        for (int nf = 0; nf < 4; ++nf) {
            bf16x8 bv = *(const bf16x8*)&xt[(16 * nf + ln) * CIN + (((4 * s + q) ^ (ln & 7)) << 3)];
            ac0[nf] = __builtin_amdgcn_mfma_f32_16x16x32_bf16(a0, bv, ac0[nf], 0, 0, 0);
            ac1[nf] = __builtin_amdgcn_mfma_f32_16x16x32_bf16(a1, bv, ac1[nf], 0, 0, 0);
        }
    }
    epilogue(ac0, ac1, b0, ylds, chs, chq, w, ln, q);
    __syncthreads();
    if (tid < 128) {
        atomicAdd(&gstat[tid], chs[tid]);
        atomicAdd(&gstat[128 + tid], chq[tid]);
    }
    // coalesced store ylds -> y0 (ws, bf16)
    {
        int o = tid >> 1, h = tid & 1;
#pragma unroll
        for (int jj = 0; jj < 4; ++jj) {
            int j = (h << 2) + jj;
            uint4 v = *(const uint4*)&ylds[(o << 6) + ((j ^ (o & 7)) << 3)];
            *(uint4*)(y0 + (size_t)(b * CO + o) * NN + n0 + (j << 3)) = v;
        }
    }
}

// ---------------- layer 1: BN0+ReLU on y0 tile -> MFMA gemm -> y1pre (bf16) in place + stats1 ----------------
__global__ __launch_bounds__(256) void k_l1(
        u16* __restrict__ y, const float* __restrict__ g0, const float* __restrict__ be0,
        const u16* __restrict__ W1b, const float* __restrict__ b1,
        float* __restrict__ gstat) {
    __shared__ u16 xt[64 * CO];           // B-tile [n][k] swz (16KB)
    __shared__ u16 ylds[CO * 64];         // (16KB)
    __shared__ float chs[CO], chq[CO], sc[CO], sh[CO];
    int tid = threadIdx.x;
    int l = tid & 63, w = tid >> 6, ln = l & 15, q = l >> 4;
    int b = blockIdx.x >> 7, n0 = (blockIdx.x & 127) << 6;
    if (tid < 128) {
        float s = gstat[tid], qv = gstat[128 + tid];   // complete: dispatch boundary
        float mu = s * (1.f / NB);
        float var = qv * (1.f / NB) - mu * mu;
        float istd = 1.f / __fsqrt_rn(var + EPS);
        float scale = g0[tid] * istd;
        sc[tid] = scale;
        sh[tid] = be0[tid] - mu * scale;
        chs[tid] = 0.f; chq[tid] = 0.f;
    }
    __syncthreads();
    // stage y0 tile with BN0+ReLU via in-register transpose; 2 x 64 channels
#pragma unroll
    for (int it = 0; it < 2; ++it) {
        int c = (it << 6) + l;
        const u16* src = y + (size_t)(b * CO + c) * NN + n0 + (w << 4);
        uint4 r0 = *(const uint4*)src;
        uint4 r1 = *(const uint4*)(src + 8);
        u16 raw[16];
        *(uint4*)&raw[0] = r0;
        *(uint4*)&raw[8] = r1;
        float scale = sc[c], shift = sh[c];
        int cc = c >> 3, clo = c & 7;
#pragma unroll
        for (int i = 0; i < 16; ++i) {
            int n = (w << 4) + i;
            float hv = fmaxf(b2f(raw[i]) * scale + shift, 0.f);
            xt[(n << 7) + ((cc ^ (i & 7)) << 3) + clo] = f2b(hv);
        }
    }
    __syncthreads();
    f32x4 ac0[4], ac1[4];
#pragma unroll
    for (int nf = 0; nf < 4; ++nf) {
        ac0[nf] = f32x4{0.f, 0.f, 0.f, 0.f};
        ac1[nf] = f32x4{0.f, 0.f, 0.f, 0.f};
    }
    const u16* w1r0 = W1b + (32 * w + ln) * CO + 8 * q;
    const u16* w1r1 = w1r0 + 16 * CO;
#pragma unroll
    for (int s = 0; s < 4; ++s) {
        bf16x8 a0 = *(const bf16x8*)(w1r0 + 32 * s);
        bf16x8 a1 = *(const bf16x8*)(w1r1 + 32 * s);
#pragma unroll
        for (int nf = 0; nf < 4; ++nf) {
            bf16x8 bv = *(const bf16x8*)&xt[((16 * nf + ln) << 7) + (((4 * s + q) ^ (ln & 7)) << 3)];
            ac0[nf] = __builtin_amdgcn_mfma_f32_16x16x32_bf16(a0, bv, ac0[nf], 0, 0, 0);
            ac1[nf] = __builtin_amdgcn_mfma_f32_16x16x32_bf16(a1, bv, ac1[nf], 0, 0, 0);
        }
    }
    epilogue(ac0, ac1, b1, ylds, chs, chq, w, ln, q);
    __syncthreads();
    if (tid < 128) {
        atomicAdd(&gstat[256 + tid], chs[tid]);
        atomicAdd(&gstat[384 + tid], chq[tid]);
    }
    // in-place store y1pre (bf16) over the same tile of ws
    {
        int o = tid >> 1, h = tid & 1;
#pragma unroll
        for (int jj = 0; jj < 4; ++jj) {
            int j = (h << 2) + jj;
            uint4 v = *(const uint4*)&ylds[(o << 6) + ((j ^ (o & 7)) << 3)];
            *(uint4*)(y + (size_t)(b * CO + o) * NN + n0 + (j << 3)) = v;
        }
    }
}

// ---------------- final BN1 + ReLU: y1pre (bf16, ws) -> d_out (f32) ----------------
__global__ __launch_bounds__(256) void k_bn1(
        const u16* __restrict__ y, const float* __restrict__ gstat,
        const float* __restrict__ g1, const float* __restrict__ be1,
        float* __restrict__ out) {
    int t = blockIdx.x * 256 + threadIdx.x;   // 4096 blocks: 8 elems/thread
    int o = (t >> 10) & 127;
    float s = gstat[256 + o], qv = gstat[384 + o];
    float mu = s * (1.f / NB);
    float var = qv * (1.f / NB) - mu * mu;
    float istd = 1.f / __fsqrt_rn(var + EPS);
    float scale = g1[o] * istd;
    float shift = be1[o] - mu * scale;
    size_t e0 = (size_t)t << 3;
    uint4 v = *(const uint4*)(y + e0);
    u16 raw[8];
    *(uint4*)raw = v;
    float r[8];
#pragma unroll
    for (int k = 0; k < 8; ++k)
        r[k] = fmaxf(b2f(raw[k]) * scale + shift, 0.f);
    *(float4*)(out + e0) = make_float4(r[0], r[1], r[2], r[3]);
    *(float4*)(out + e0 + 4) = make_float4(r[4], r[5], r[6], r[7]);
}

extern "C" void kernel_launch(void* const* d_in, const int* in_sizes, int n_in,
                              void* d_out, int out_size, void* d_ws, size_t ws_size,
                              hipStream_t stream) {
    const float* lt = (const float*)d_in[0];
    const float* lp = (const float*)d_in[1];
    const float* lf = (const float*)d_in[2];
    const float* ht = (const float*)d_in[3];
    const float* hp = (const float*)d_in[4];
    const float* hf = (const float*)d_in[5];
    const float* W0 = (const float*)d_in[6];
    const float* b0 = (const float*)d_in[7];
    const float* g0 = (const float*)d_in[8];
    const float* be0 = (const float*)d_in[9];
    const float* W1 = (const float*)d_in[10];
    const float* b1 = (const float*)d_in[11];
    const float* g1 = (const float*)d_in[12];
    const float* be1 = (const float*)d_in[13];

    char* ws = (char*)d_ws;
    u16* y0 = (u16*)ws;                         // 16.78 MB (y0, then y1pre in place)
    u16* hT = (u16*)(ws + 16777216);            // 4.19 MB
    int* idx = (int*)(ws + 20971520);           // 256 KB
    float* gstat = (float*)(ws + 21233664);     // 2 KB: gs0,gq0,gs1,gq1
    u16* W0b = (u16*)(ws + 21235712);           // 48 KB
    u16* W1b = (u16*)(ws + 21284864);           // 32 KB -> end 21317632 (ws-proven)

    hipMemsetAsync(gstat, 0, 512 * sizeof(float), stream);
    k_prep_w<<<96, 256, 0, stream>>>(W0, W1, W0b, W1b);
    k_prep_h<<<dim3(8, 32, 2), 256, 0, stream>>>(hf, hT);
    k_argmin<<<1024, 256, 0, stream>>>(lt, lp, ht, hp, idx);
    k_l0<<<1024, 256, 0, stream>>>(lf, hT, idx, W0b, b0, y0, gstat);
    k_l1<<<1024, 256, 0, stream>>>(y0, g0, be0, W1b, b1, gstat);
    k_bn1<<<4096, 256, 0, stream>>>(y0, gstat, g1, be1, (float*)d_out);
}

// Round 6
// 143.620 us; speedup vs baseline: 2.1480x; 1.1645x over previous
//
#include <hip/hip_runtime.h>
#include <hip/hip_bf16.h>

#define BB 8
#define NN 8192
#define MM 2048
#define C1 64
#define C2 128
#define CIN 192
#define CO 128
#define NB (BB*NN)
#define EPS 1e-5f

typedef unsigned short u16;
typedef unsigned int u32;
typedef __bf16 bf16_t;
typedef bf16_t bf16x8 __attribute__((ext_vector_type(8)));
typedef float f32x4 __attribute__((ext_vector_type(4)));

static __device__ __forceinline__ float b2f(u16 u) { return __uint_as_float(((u32)u) << 16); }
static __device__ __forceinline__ u16 f2b(float f) {
    __hip_bfloat16 h = __float2bfloat16(f);
    u16 u; __builtin_memcpy(&u, &h, 2); return u;
}

// ---------------- weights f32 -> bf16 (same layout) ----------------
__global__ void k_prep_w(const float* __restrict__ W0, const float* __restrict__ W1,
                         u16* __restrict__ W0b, u16* __restrict__ W1b) {
    int t = blockIdx.x * 256 + threadIdx.x;      // 96 blocks = 24576 threads
    if (t < CIN * CO) W0b[t] = f2b(W0[t]);
    if (t < CO * CO)  W1b[t] = f2b(W1[t]);
}

// ---------------- high_feats transpose: f32 [B][C2][M] -> bf16 [B][M][C2] ----------------
__global__ void k_prep_h(const float* __restrict__ hf, u16* __restrict__ hT) {
    __shared__ u16 s[64][65];
    int b = blockIdx.x, m0 = blockIdx.y * 64, c0 = blockIdx.z * 64;
    for (int e = threadIdx.x; e < 64 * 64; e += 256) {
        int i = e >> 6, j = e & 63;                 // i: c, j: m (coalesced in m)
        s[i][j] = f2b(hf[(b * C2 + c0 + i) * MM + m0 + j]);
    }
    __syncthreads();
    for (int e = threadIdx.x; e < 64 * 64; e += 256) {
        int ii = e & 63, jj = e >> 6;               // coalesced in c
        hT[(b * MM + m0 + jj) * C2 + c0 + ii] = s[ii][jj];
    }
}

// ---------------- nearest neighbor: branchless exact scan ----------------
// Scan on d2 (rn mul,mul,add - no FMA, = np) keeping per chain the LAST filter
// hit (strictly-decreasing d2 sequence) AND the PREVIOUS hit. np's argmin is
// over sqrt(d2) with first-index ties; a sqrt-tie can only promote the
// immediately-previous hit (sqrt monotone between d2 values), so at the end:
// if fsqrt_rn(prev)==fsqrt_rn(last) the earlier index wins. Exact up to
// triple-ties within ~1.5ulp of d2 (P~1e-10). Merges compare (sqrt, idx).
__global__ __launch_bounds__(256) void k_argmin(
        const float* __restrict__ lt_, const float* __restrict__ lp_,
        const float* __restrict__ ht_, const float* __restrict__ hp_,
        int* __restrict__ idx) {
    __shared__ float2 hs[8 * 260];                  // part stride 260: banks 8p%32, 2-way free
    int b = blockIdx.x >> 8;                        // 256 blocks per batch
    int n0 = (blockIdx.x & 255) << 5;               // 32 queries per block
    int tid = threadIdx.x;
    for (int e = tid; e < MM; e += 256) {
        int p = e >> 8, i = e & 255;
        hs[p * 260 + i] = make_float2(ht_[b * MM + e], hp_[b * MM + e]);
    }
    __syncthreads();
    int q = tid >> 3, p = tid & 7;                  // 32 queries x 8 m-parts per block
    float lt = lt_[b * NN + n0 + q];
    float lp = lp_[b * NN + n0 + q];
    // per-chain state: last hit (dl, il) and previous hit (dpv, ip)
    float dl[4] = {1e30f, 1e30f, 1e30f, 1e30f};
    float dpv[4] = {1e30f, 1e30f, 1e30f, 1e30f};
    int il[4] = {0, 0, 0, 0}, ip[4] = {0, 0, 0, 0};
    const float2* hp2 = &hs[p * 260];
    int mbase = p << 8;
#pragma unroll 8
    for (int i4 = 0; i4 < 64; ++i4) {               // 4 interleaved chains: cand 4*i4+c
#pragma unroll
        for (int c = 0; c < 4; ++c) {
            float2 h = hp2[i4 * 4 + c];             // 32B/iter contiguous -> 2x ds_read_b128
            float dt = lt - h.x, dp = lp - h.y;
            float d2 = __fadd_rn(__fmul_rn(dt, dt), __fmul_rn(dp, dp)); // no-FMA = np
            bool hit = d2 < dl[c];                  // strict <
            dpv[c] = hit ? dl[c] : dpv[c];
            ip[c] = hit ? il[c] : ip[c];
            dl[c] = hit ? d2 : dl[c];
            il[c] = hit ? mbase + i4 * 4 + c : il[c];
        }
    }
    // resolve chains: sqrt-tie promotes prev; then merge by (sqrt, idx)
    float bs = 1e30f; int bm = 0x7fffffff;
#pragma unroll
    for (int c = 0; c < 4; ++c) {
        float sl = __fsqrt_rn(dl[c]);
        float sp = __fsqrt_rn(dpv[c]);
        int cand = (sp == sl) ? ip[c] : il[c];      // prev has smaller index
        if (sl < bs || (sl == bs && cand < bm)) { bs = sl; bm = cand; }
    }
#pragma unroll
    for (int d = 1; d <= 4; d <<= 1) {              // merge 8 parts (lanes 8q+p)
        float ov = __shfl_xor(bs, d, 64);
        int om = __shfl_xor(bm, d, 64);
        if (ov < bs || (ov == bs && om < bm)) { bs = ov; bm = om; }
    }
    if (p == 0) idx[b * NN + n0 + q] = bm;
}

// epilogue: bias add, per-channel sum/sumsq (f32, pre-rounding), bf16 store to ylds[o][n swz]
static __device__ __forceinline__ void epilogue(
        f32x4* ac0, f32x4* ac1, const float* bias, u16* yl,
        float* chs, float* chq, int w, int ln, int q) {
#pragma unroll
    for (int mf = 0; mf < 2; ++mf) {
        f32x4* A = mf ? ac1 : ac0;
        int chb = 32 * w + 16 * mf + 4 * q;
        float bs[4], ss[4] = {0.f, 0.f, 0.f, 0.f}, sq[4] = {0.f, 0.f, 0.f, 0.f};
#pragma unroll
        for (int r = 0; r < 4; ++r) bs[r] = bias[chb + r];
#pragma unroll
        for (int nf = 0; nf < 4; ++nf) {
            int n = (nf << 4) + ln;
#pragma unroll
            for (int r = 0; r < 4; ++r) {
                float y = A[nf][r] + bs[r];
                ss[r] += y; sq[r] += y * y;
                int o = chb + r;
                yl[(o << 6) + (n ^ ((o & 7) << 3))] = f2b(y);
            }
        }
#pragma unroll
        for (int r = 0; r < 4; ++r) {
            float v = ss[r], u2 = sq[r];
#pragma unroll
            for (int d = 1; d < 16; d <<= 1) {
                v += __shfl_xor(v, d, 64);
                u2 += __shfl_xor(u2, d, 64);
            }
            if (ln == 0) { atomicAdd(&chs[chb + r], v); atomicAdd(&chq[chb + r], u2); }
        }
    }
}

// ---------------- layer 0: gather + MFMA gemm + bias -> y0 (ws, bf16) + stats0 ----------------
__global__ __launch_bounds__(256) void k_l0(
        const float* __restrict__ lf, const u16* __restrict__ hT, const int* __restrict__ idx,
        const u16* __restrict__ W0b, const float* __restrict__ b0,
        u16* __restrict__ y0, float* __restrict__ gstat) {
    __shared__ u16 xt[64 * CIN];          // B-tile [n][k] XOR-chunk-swizzled (24.5KB)
    __shared__ u16 ylds[CO * 64];         // y tile [o][n swz] (16KB)
    __shared__ float chs[CO], chq[CO];
    __shared__ int idxs[64];
    int tid = threadIdx.x;
    int l = tid & 63, w = tid >> 6, ln = l & 15, q = l >> 4;
    int b = blockIdx.x >> 7, n0 = (blockIdx.x & 127) << 6;
    if (tid < 64) idxs[tid] = idx[b * NN + n0 + tid];
    if (tid < 128) { chs[tid] = 0.f; chq[tid] = 0.f; }
    __syncthreads();
    // stage low_feats rows 0..63 via in-register transpose (lane = channel, f32 -> bf16)
    {
        const float* src = lf + (size_t)(b * C1 + l) * NN + n0 + (w << 4);
        float4 f0 = *(const float4*)src;
        float4 f1 = *(const float4*)(src + 4);
        float4 f2 = *(const float4*)(src + 8);
        float4 f3 = *(const float4*)(src + 12);
        float v[16] = {f0.x, f0.y, f0.z, f0.w, f1.x, f1.y, f1.z, f1.w,
                       f2.x, f2.y, f2.z, f2.w, f3.x, f3.y, f3.z, f3.w};
        int cc = l >> 3, clo = l & 7;
#pragma unroll
        for (int i = 0; i < 16; ++i) {
            int n = (w << 4) + i;
            xt[n * CIN + ((cc ^ (i & 7)) << 3) + clo] = f2b(v[i]);
        }
    }
    // gather nearest high rows (contiguous 256B per row from bf16 hT)
    for (int e = tid; e < 1024; e += 256) {
        int n = e >> 4, c16 = e & 15;
        uint4 v = *(const uint4*)(hT + (size_t)(b * MM + idxs[n]) * C2 + (c16 << 3));
        *(uint4*)&xt[n * CIN + (((8 + c16) ^ (n & 7)) << 3)] = v;
    }
    __syncthreads();
    f32x4 ac0[4], ac1[4];
#pragma unroll
    for (int nf = 0; nf < 4; ++nf) {
        ac0[nf] = f32x4{0.f, 0.f, 0.f, 0.f};
        ac1[nf] = f32x4{0.f, 0.f, 0.f, 0.f};
    }
    const u16* w0r0 = W0b + (32 * w + ln) * CIN + 8 * q;
    const u16* w0r1 = w0r0 + 16 * CIN;
#pragma unroll
    for (int s = 0; s < 6; ++s) {
        bf16x8 a0 = *(const bf16x8*)(w0r0 + 32 * s);
        bf16x8 a1 = *(const bf16x8*)(w0r1 + 32 * s);
#pragma unroll
        for (int nf = 0; nf < 4; ++nf) {
            bf16x8 bv = *(const bf16x8*)&xt[(16 * nf + ln) * CIN + (((4 * s + q) ^ (ln & 7)) << 3)];
            ac0[nf] = __builtin_amdgcn_mfma_f32_16x16x32_bf16(a0, bv, ac0[nf], 0, 0, 0);
            ac1[nf] = __builtin_amdgcn_mfma_f32_16x16x32_bf16(a1, bv, ac1[nf], 0, 0, 0);
        }
    }
    epilogue(ac0, ac1, b0, ylds, chs, chq, w, ln, q);
    __syncthreads();
    if (tid < 128) {
        atomicAdd(&gstat[tid], chs[tid]);
        atomicAdd(&gstat[128 + tid], chq[tid]);
    }
    // coalesced store ylds -> y0 (ws, bf16)
    {
        int o = tid >> 1, h = tid & 1;
#pragma unroll
        for (int jj = 0; jj < 4; ++jj) {
            int j = (h << 2) + jj;
            uint4 v = *(const uint4*)&ylds[(o << 6) + ((j ^ (o & 7)) << 3)];
            *(uint4*)(y0 + (size_t)(b * CO + o) * NN + n0 + (j << 3)) = v;
        }
    }
}

// ---------------- layer 1: BN0+ReLU on y0 tile -> MFMA gemm -> y1pre (bf16) in place + stats1 ----------------
__global__ __launch_bounds__(256) void k_l1(
        u16* __restrict__ y, const float* __restrict__ g0, const float* __restrict__ be0,
        const u16* __restrict__ W1b, const float* __restrict__ b1,
        float* __restrict__ gstat) {
    __shared__ u16 xt[64 * CO];           // B-tile [n][k] swz (16KB)
    __shared__ u16 ylds[CO * 64];         // (16KB)
    __shared__ float chs[CO], chq[CO], sc[CO], sh[CO];
    int tid = threadIdx.x;
    int l = tid & 63, w = tid >> 6, ln = l & 15, q = l >> 4;
    int b = blockIdx.x >> 7, n0 = (blockIdx.x & 127) << 6;
    if (tid < 128) {
        float s = gstat[tid], qv = gstat[128 + tid];   // complete: dispatch boundary
        float mu = s * (1.f / NB);
        float var = qv * (1.f / NB) - mu * mu;
        float istd = 1.f / __fsqrt_rn(var + EPS);
        float scale = g0[tid] * istd;
        sc[tid] = scale;
        sh[tid] = be0[tid] - mu * scale;
        chs[tid] = 0.f; chq[tid] = 0.f;
    }
    __syncthreads();
    // stage y0 tile with BN0+ReLU via in-register transpose; 2 x 64 channels
#pragma unroll
    for (int it = 0; it < 2; ++it) {
        int c = (it << 6) + l;
        const u16* src = y + (size_t)(b * CO + c) * NN + n0 + (w << 4);
        uint4 r0 = *(const uint4*)src;
        uint4 r1 = *(const uint4*)(src + 8);
        u16 raw[16];
        *(uint4*)&raw[0] = r0;
        *(uint4*)&raw[8] = r1;
        float scale = sc[c], shift = sh[c];
        int cc = c >> 3, clo = c & 7;
#pragma unroll
        for (int i = 0; i < 16; ++i) {
            int n = (w << 4) + i;
            float hv = fmaxf(b2f(raw[i]) * scale + shift, 0.f);
            xt[(n << 7) + ((cc ^ (i & 7)) << 3) + clo] = f2b(hv);
        }
    }
    __syncthreads();
    f32x4 ac0[4], ac1[4];
#pragma unroll
    for (int nf = 0; nf < 4; ++nf) {
        ac0[nf] = f32x4{0.f, 0.f, 0.f, 0.f};
        ac1[nf] = f32x4{0.f, 0.f, 0.f, 0.f};
    }
    const u16* w1r0 = W1b + (32 * w + ln) * CO + 8 * q;
    const u16* w1r1 = w1r0 + 16 * CO;
#pragma unroll
    for (int s = 0; s < 4; ++s) {
        bf16x8 a0 = *(const bf16x8*)(w1r0 + 32 * s);
        bf16x8 a1 = *(const bf16x8*)(w1r1 + 32 * s);
#pragma unroll
        for (int nf = 0; nf < 4; ++nf) {
            bf16x8 bv = *(const bf16x8*)&xt[((16 * nf + ln) << 7) + (((4 * s + q) ^ (ln & 7)) << 3)];
            ac0[nf] = __builtin_amdgcn_mfma_f32_16x16x32_bf16(a0, bv, ac0[nf], 0, 0, 0);
            ac1[nf] = __builtin_amdgcn_mfma_f32_16x16x32_bf16(a1, bv, ac1[nf], 0, 0, 0);
        }
    }
    epilogue(ac0, ac1, b1, ylds, chs, chq, w, ln, q);
    __syncthreads();
    if (tid < 128) {
        atomicAdd(&gstat[256 + tid], chs[tid]);
        atomicAdd(&gstat[384 + tid], chq[tid]);
    }
    // in-place store y1pre (bf16) over the same tile of ws
    {
        int o = tid >> 1, h = tid & 1;
#pragma unroll
        for (int jj = 0; jj < 4; ++jj) {
            int j = (h << 2) + jj;
            uint4 v = *(const uint4*)&ylds[(o << 6) + ((j ^ (o & 7)) << 3)];
            *(uint4*)(y + (size_t)(b * CO + o) * NN + n0 + (j << 3)) = v;
        }
    }
}

// ---------------- final BN1 + ReLU: y1pre (bf16, ws) -> d_out (f32) ----------------
__global__ __launch_bounds__(256) void k_bn1(
        const u16* __restrict__ y, const float* __restrict__ gstat,
        const float* __restrict__ g1, const float* __restrict__ be1,
        float* __restrict__ out) {
    int t = blockIdx.x * 256 + threadIdx.x;   // 4096 blocks: 8 elems/thread
    int o = (t >> 10) & 127;
    float s = gstat[256 + o], qv = gstat[384 + o];
    float mu = s * (1.f / NB);
    float var = qv * (1.f / NB) - mu * mu;
    float istd = 1.f / __fsqrt_rn(var + EPS);
    float scale = g1[o] * istd;
    float shift = be1[o] - mu * scale;
    size_t e0 = (size_t)t << 3;
    uint4 v = *(const uint4*)(y + e0);
    u16 raw[8];
    *(uint4*)raw = v;
    float r[8];
#pragma unroll
    for (int k = 0; k < 8; ++k)
        r[k] = fmaxf(b2f(raw[k]) * scale + shift, 0.f);
    *(float4*)(out + e0) = make_float4(r[0], r[1], r[2], r[3]);
    *(float4*)(out + e0 + 4) = make_float4(r[4], r[5], r[6], r[7]);
}

extern "C" void kernel_launch(void* const* d_in, const int* in_sizes, int n_in,
                              void* d_out, int out_size, void* d_ws, size_t ws_size,
                              hipStream_t stream) {
    const float* lt = (const float*)d_in[0];
    const float* lp = (const float*)d_in[1];
    const float* lf = (const float*)d_in[2];
    const float* ht = (const float*)d_in[3];
    const float* hp = (const float*)d_in[4];
    const float* hf = (const float*)d_in[5];
    const float* W0 = (const float*)d_in[6];
    const float* b0 = (const float*)d_in[7];
    const float* g0 = (const float*)d_in[8];
    const float* be0 = (const float*)d_in[9];
    const float* W1 = (const float*)d_in[10];
    const float* b1 = (const float*)d_in[11];
    const float* g1 = (const float*)d_in[12];
    const float* be1 = (const float*)d_in[13];

    char* ws = (char*)d_ws;
    u16* y0 = (u16*)ws;                         // 16.78 MB (y0, then y1pre in place)
    u16* hT = (u16*)(ws + 16777216);            // 4.19 MB
    int* idx = (int*)(ws + 20971520);           // 256 KB
    float* gstat = (float*)(ws + 21233664);     // 2 KB: gs0,gq0,gs1,gq1
    u16* W0b = (u16*)(ws + 21235712);           // 48 KB
    u16* W1b = (u16*)(ws + 21284864);           // 32 KB -> end 21317632 (ws-proven)

    hipMemsetAsync(gstat, 0, 512 * sizeof(float), stream);
    k_prep_w<<<96, 256, 0, stream>>>(W0, W1, W0b, W1b);
    k_prep_h<<<dim3(8, 32, 2), 256, 0, stream>>>(hf, hT);
    k_argmin<<<2048, 256, 0, stream>>>(lt, lp, ht, hp, idx);
    k_l0<<<1024, 256, 0, stream>>>(lf, hT, idx, W0b, b0, y0, gstat);
    k_l1<<<1024, 256, 0, stream>>>(y0, g0, be0, W1b, b1, gstat);
    k_bn1<<<4096, 256, 0, stream>>>(y0, gstat, g1, be1, (float*)d_out);
}

// Round 7
// 110.225 us; speedup vs baseline: 2.7988x; 1.3030x over previous
//
#include <hip/hip_runtime.h>
#include <hip/hip_bf16.h>

#define BB 8
#define NN 8192
#define MM 2048
#define C1 64
#define C2 128
#define CIN 192
#define CO 128
#define NB (BB*NN)
#define EPS 1e-5f

typedef unsigned short u16;
typedef unsigned int u32;
typedef __bf16 bf16_t;
typedef bf16_t bf16x8 __attribute__((ext_vector_type(8)));
typedef float f32x4 __attribute__((ext_vector_type(4)));

static __device__ __forceinline__ float b2f(u16 u) { return __uint_as_float(((u32)u) << 16); }
static __device__ __forceinline__ u16 f2b(float f) {
    __hip_bfloat16 h = __float2bfloat16(f);
    u16 u; __builtin_memcpy(&u, &h, 2); return u;
}

// ---------------- weights f32 -> bf16 (same layout) ----------------
__global__ void k_prep_w(const float* __restrict__ W0, const float* __restrict__ W1,
                         u16* __restrict__ W0b, u16* __restrict__ W1b) {
    int t = blockIdx.x * 256 + threadIdx.x;      // 96 blocks = 24576 threads
    if (t < CIN * CO) W0b[t] = f2b(W0[t]);
    if (t < CO * CO)  W1b[t] = f2b(W1[t]);
}

// ---------------- high_feats transpose: f32 [B][C2][M] -> bf16 [B][M][C2] ----------------
__global__ void k_prep_h(const float* __restrict__ hf, u16* __restrict__ hT) {
    __shared__ u16 s[64][65];
    int b = blockIdx.x, m0 = blockIdx.y * 64, c0 = blockIdx.z * 64;
    for (int e = threadIdx.x; e < 64 * 64; e += 256) {
        int i = e >> 6, j = e & 63;                 // i: c, j: m (coalesced in m)
        s[i][j] = f2b(hf[(b * C2 + c0 + i) * MM + m0 + j]);
    }
    __syncthreads();
    for (int e = threadIdx.x; e < 64 * 64; e += 256) {
        int ii = e & 63, jj = e >> 6;               // coalesced in c
        hT[(b * MM + m0 + jj) * C2 + c0 + ii] = s[ii][jj];
    }
}

// ---------------- nearest neighbor: branchless exact scan ----------------
// (unchanged from round 6 - verified correct & fast)
__global__ __launch_bounds__(256) void k_argmin(
        const float* __restrict__ lt_, const float* __restrict__ lp_,
        const float* __restrict__ ht_, const float* __restrict__ hp_,
        int* __restrict__ idx) {
    __shared__ float2 hs[8 * 260];                  // part stride 260: 2-way free
    int b = blockIdx.x >> 8;                        // 256 blocks per batch
    int n0 = (blockIdx.x & 255) << 5;               // 32 queries per block
    int tid = threadIdx.x;
    for (int e = tid; e < MM; e += 256) {
        int p = e >> 8, i = e & 255;
        hs[p * 260 + i] = make_float2(ht_[b * MM + e], hp_[b * MM + e]);
    }
    __syncthreads();
    int q = tid >> 3, p = tid & 7;                  // 32 queries x 8 m-parts per block
    float lt = lt_[b * NN + n0 + q];
    float lp = lp_[b * NN + n0 + q];
    float dl[4] = {1e30f, 1e30f, 1e30f, 1e30f};
    float dpv[4] = {1e30f, 1e30f, 1e30f, 1e30f};
    int il[4] = {0, 0, 0, 0}, ip[4] = {0, 0, 0, 0};
    const float2* hp2 = &hs[p * 260];
    int mbase = p << 8;
#pragma unroll 8
    for (int i4 = 0; i4 < 64; ++i4) {
#pragma unroll
        for (int c = 0; c < 4; ++c) {
            float2 h = hp2[i4 * 4 + c];
            float dt = lt - h.x, dp = lp - h.y;
            float d2 = __fadd_rn(__fmul_rn(dt, dt), __fmul_rn(dp, dp)); // no-FMA = np
            bool hit = d2 < dl[c];
            dpv[c] = hit ? dl[c] : dpv[c];
            ip[c] = hit ? il[c] : ip[c];
            dl[c] = hit ? d2 : dl[c];
            il[c] = hit ? mbase + i4 * 4 + c : il[c];
        }
    }
    float bs = 1e30f; int bm = 0x7fffffff;
#pragma unroll
    for (int c = 0; c < 4; ++c) {
        float sl = __fsqrt_rn(dl[c]);
        float sp = __fsqrt_rn(dpv[c]);
        int cand = (sp == sl) ? ip[c] : il[c];
        if (sl < bs || (sl == bs && cand < bm)) { bs = sl; bm = cand; }
    }
#pragma unroll
    for (int d = 1; d <= 4; d <<= 1) {
        float ov = __shfl_xor(bs, d, 64);
        int om = __shfl_xor(bm, d, 64);
        if (ov < bs || (ov == bs && om < bm)) { bs = ov; bm = om; }
    }
    if (p == 0) idx[b * NN + n0 + q] = bm;
}

// epilogue: bias add, per-channel sum/sumsq into LDS chs/chq, bf16 store to ylds
static __device__ __forceinline__ void epilogue(
        f32x4* ac0, f32x4* ac1, const float* bias, u16* yl,
        float* chs, float* chq, int w, int ln, int q) {
#pragma unroll
    for (int mf = 0; mf < 2; ++mf) {
        f32x4* A = mf ? ac1 : ac0;
        int chb = 32 * w + 16 * mf + 4 * q;
        float bs[4], ss[4] = {0.f, 0.f, 0.f, 0.f}, sq[4] = {0.f, 0.f, 0.f, 0.f};
#pragma unroll
        for (int r = 0; r < 4; ++r) bs[r] = bias[chb + r];
#pragma unroll
        for (int nf = 0; nf < 4; ++nf) {
            int n = (nf << 4) + ln;
#pragma unroll
            for (int r = 0; r < 4; ++r) {
                float y = A[nf][r] + bs[r];
                ss[r] += y; sq[r] += y * y;
                int o = chb + r;
                yl[(o << 6) + (n ^ ((o & 7) << 3))] = f2b(y);
            }
        }
#pragma unroll
        for (int r = 0; r < 4; ++r) {
            float v = ss[r], u2 = sq[r];
#pragma unroll
            for (int d = 1; d < 16; d <<= 1) {
                v += __shfl_xor(v, d, 64);
                u2 += __shfl_xor(u2, d, 64);
            }
            if (ln == 0) { atomicAdd(&chs[chb + r], v); atomicAdd(&chq[chb + r], u2); }
        }
    }
}

// ---------------- deterministic stat reduce: gpart[1024][256] -> gout[256] ----------------
__global__ __launch_bounds__(256) void k_red(const float* __restrict__ gpart,
                                             float* __restrict__ gout) {
    __shared__ float part[4];
    int c = blockIdx.x;                    // one block per channel-slot (256)
    int t = threadIdx.x;
    float s = 0.f;
#pragma unroll
    for (int k = 0; k < 4; ++k)
        s += gpart[(t + (k << 8)) * 256 + c];
#pragma unroll
    for (int d = 1; d < 64; d <<= 1)
        s += __shfl_xor(s, d, 64);
    if ((t & 63) == 0) part[t >> 6] = s;
    __syncthreads();
    if (t == 0) gout[c] = (part[0] + part[1]) + (part[2] + part[3]);
}

// ---------------- layer 0: gather + MFMA gemm + bias -> y0 (ws, bf16) + stat partials ----------------
__global__ __launch_bounds__(256) void k_l0(
        const float* __restrict__ lf, const u16* __restrict__ hT, const int* __restrict__ idx,
        const u16* __restrict__ W0b, const float* __restrict__ b0,
        u16* __restrict__ y0, float* __restrict__ gpart) {
    __shared__ u16 xt[64 * CIN];          // B-tile [n][k] XOR-chunk-swizzled (24.5KB)
    __shared__ u16 ylds[CO * 64];         // y tile [o][n swz] (16KB)
    __shared__ float chs[CO], chq[CO];
    __shared__ int idxs[64];
    int tid = threadIdx.x;
    int l = tid & 63, w = tid >> 6, ln = l & 15, q = l >> 4;
    int b = blockIdx.x >> 7, n0 = (blockIdx.x & 127) << 6;
    if (tid < 64) idxs[tid] = idx[b * NN + n0 + tid];
    if (tid < 128) { chs[tid] = 0.f; chq[tid] = 0.f; }
    __syncthreads();
    // stage low_feats rows 0..63 via in-register transpose (lane = channel, f32 -> bf16)
    {
        const float* src = lf + (size_t)(b * C1 + l) * NN + n0 + (w << 4);
        float4 f0 = *(const float4*)src;
        float4 f1 = *(const float4*)(src + 4);
        float4 f2 = *(const float4*)(src + 8);
        float4 f3 = *(const float4*)(src + 12);
        float v[16] = {f0.x, f0.y, f0.z, f0.w, f1.x, f1.y, f1.z, f1.w,
                       f2.x, f2.y, f2.z, f2.w, f3.x, f3.y, f3.z, f3.w};
        int cc = l >> 3, clo = l & 7;
#pragma unroll
        for (int i = 0; i < 16; ++i) {
            int n = (w << 4) + i;
            xt[n * CIN + ((cc ^ (i & 7)) << 3) + clo] = f2b(v[i]);
        }
    }
    // gather nearest high rows (contiguous 256B per row from bf16 hT)
    for (int e = tid; e < 1024; e += 256) {
        int n = e >> 4, c16 = e & 15;
        uint4 v = *(const uint4*)(hT + (size_t)(b * MM + idxs[n]) * C2 + (c16 << 3));
        *(uint4*)&xt[n * CIN + (((8 + c16) ^ (n & 7)) << 3)] = v;
    }
    __syncthreads();
    f32x4 ac0[4], ac1[4];
#pragma unroll
    for (int nf = 0; nf < 4; ++nf) {
        ac0[nf] = f32x4{0.f, 0.f, 0.f, 0.f};
        ac1[nf] = f32x4{0.f, 0.f, 0.f, 0.f};
    }
    const u16* w0r0 = W0b + (32 * w + ln) * CIN + 8 * q;
    const u16* w0r1 = w0r0 + 16 * CIN;
#pragma unroll
    for (int s = 0; s < 6; ++s) {
        bf16x8 a0 = *(const bf16x8*)(w0r0 + 32 * s);
        bf16x8 a1 = *(const bf16x8*)(w0r1 + 32 * s);
#pragma unroll
        for (int nf = 0; nf < 4; ++nf) {
            bf16x8 bv = *(const bf16x8*)&xt[(16 * nf + ln) * CIN + (((4 * s + q) ^ (ln & 7)) << 3)];
            ac0[nf] = __builtin_amdgcn_mfma_f32_16x16x32_bf16(a0, bv, ac0[nf], 0, 0, 0);
            ac1[nf] = __builtin_amdgcn_mfma_f32_16x16x32_bf16(a1, bv, ac1[nf], 0, 0, 0);
        }
    }
    epilogue(ac0, ac1, b0, ylds, chs, chq, w, ln, q);
    __syncthreads();
    // per-block stat partials: unique coalesced slot, no global atomics
    gpart[blockIdx.x * 256 + tid] = (tid < 128) ? chs[tid] : chq[tid - 128];
    // coalesced store ylds -> y0 (ws, bf16)
    {
        int o = tid >> 1, h = tid & 1;
#pragma unroll
        for (int jj = 0; jj < 4; ++jj) {
            int j = (h << 2) + jj;
            uint4 v = *(const uint4*)&ylds[(o << 6) + ((j ^ (o & 7)) << 3)];
            *(uint4*)(y0 + (size_t)(b * CO + o) * NN + n0 + (j << 3)) = v;
        }
    }
}

// ---------------- layer 1: BN0+ReLU on y0 tile -> MFMA gemm -> y1pre in place + stat partials ----------------
__global__ __launch_bounds__(256) void k_l1(
        u16* __restrict__ y, const float* __restrict__ g0, const float* __restrict__ be0,
        const u16* __restrict__ W1b, const float* __restrict__ b1,
        const float* __restrict__ gstat, float* __restrict__ gpart) {
    __shared__ u16 xt[64 * CO];           // B-tile [n][k] swz (16KB)
    __shared__ u16 ylds[CO * 64];         // (16KB)
    __shared__ float chs[CO], chq[CO], sc[CO], sh[CO];
    int tid = threadIdx.x;
    int l = tid & 63, w = tid >> 6, ln = l & 15, q = l >> 4;
    int b = blockIdx.x >> 7, n0 = (blockIdx.x & 127) << 6;
    if (tid < 128) {
        float s = gstat[tid], qv = gstat[128 + tid];   // complete: dispatch boundary
        float mu = s * (1.f / NB);
        float var = qv * (1.f / NB) - mu * mu;
        float istd = 1.f / __fsqrt_rn(var + EPS);
        float scale = g0[tid] * istd;
        sc[tid] = scale;
        sh[tid] = be0[tid] - mu * scale;
        chs[tid] = 0.f; chq[tid] = 0.f;
    }
    __syncthreads();
    // stage y0 tile with BN0+ReLU via in-register transpose; 2 x 64 channels
#pragma unroll
    for (int it = 0; it < 2; ++it) {
        int c = (it << 6) + l;
        const u16* src = y + (size_t)(b * CO + c) * NN + n0 + (w << 4);
        uint4 r0 = *(const uint4*)src;
        uint4 r1 = *(const uint4*)(src + 8);
        u16 raw[16];
        *(uint4*)&raw[0] = r0;
        *(uint4*)&raw[8] = r1;
        float scale = sc[c], shift = sh[c];
        int cc = c >> 3, clo = c & 7;
#pragma unroll
        for (int i = 0; i < 16; ++i) {
            int n = (w << 4) + i;
            float hv = fmaxf(b2f(raw[i]) * scale + shift, 0.f);
            xt[(n << 7) + ((cc ^ (i & 7)) << 3) + clo] = f2b(hv);
        }
    }
    __syncthreads();
    f32x4 ac0[4], ac1[4];
#pragma unroll
    for (int nf = 0; nf < 4; ++nf) {
        ac0[nf] = f32x4{0.f, 0.f, 0.f, 0.f};
        ac1[nf] = f32x4{0.f, 0.f, 0.f, 0.f};
    }
    const u16* w1r0 = W1b + (32 * w + ln) * CO + 8 * q;
    const u16* w1r1 = w1r0 + 16 * CO;
#pragma unroll
    for (int s = 0; s < 4; ++s) {
        bf16x8 a0 = *(const bf16x8*)(w1r0 + 32 * s);
        bf16x8 a1 = *(const bf16x8*)(w1r1 + 32 * s);
#pragma unroll
        for (int nf = 0; nf < 4; ++nf) {
            bf16x8 bv = *(const bf16x8*)&xt[((16 * nf + ln) << 7) + (((4 * s + q) ^ (ln & 7)) << 3)];
            ac0[nf] = __builtin_amdgcn_mfma_f32_16x16x32_bf16(a0, bv, ac0[nf], 0, 0, 0);
            ac1[nf] = __builtin_amdgcn_mfma_f32_16x16x32_bf16(a1, bv, ac1[nf], 0, 0, 0);
        }
    }
    epilogue(ac0, ac1, b1, ylds, chs, chq, w, ln, q);
    __syncthreads();
    gpart[blockIdx.x * 256 + tid] = (tid < 128) ? chs[tid] : chq[tid - 128];
    // in-place store y1pre (bf16) over the same tile of ws
    {
        int o = tid >> 1, h = tid & 1;
#pragma unroll
        for (int jj = 0; jj < 4; ++jj) {
            int j = (h << 2) + jj;
            uint4 v = *(const uint4*)&ylds[(o << 6) + ((j ^ (o & 7)) << 3)];
            *(uint4*)(y + (size_t)(b * CO + o) * NN + n0 + (j << 3)) = v;
        }
    }
}

// ---------------- final BN1 + ReLU: y1pre (bf16, ws) -> d_out (f32) ----------------
__global__ __launch_bounds__(256) void k_bn1(
        const u16* __restrict__ y, const float* __restrict__ gstat,
        const float* __restrict__ g1, const float* __restrict__ be1,
        float* __restrict__ out) {
    int t = blockIdx.x * 256 + threadIdx.x;   // 4096 blocks: 8 elems/thread
    int o = (t >> 10) & 127;
    float s = gstat[256 + o], qv = gstat[384 + o];
    float mu = s * (1.f / NB);
    float var = qv * (1.f / NB) - mu * mu;
    float istd = 1.f / __fsqrt_rn(var + EPS);
    float scale = g1[o] * istd;
    float shift = be1[o] - mu * scale;
    size_t e0 = (size_t)t << 3;
    uint4 v = *(const uint4*)(y + e0);
    u16 raw[8];
    *(uint4*)raw = v;
    float r[8];
#pragma unroll
    for (int k = 0; k < 8; ++k)
        r[k] = fmaxf(b2f(raw[k]) * scale + shift, 0.f);
    *(float4*)(out + e0) = make_float4(r[0], r[1], r[2], r[3]);
    *(float4*)(out + e0 + 4) = make_float4(r[4], r[5], r[6], r[7]);
}

extern "C" void kernel_launch(void* const* d_in, const int* in_sizes, int n_in,
                              void* d_out, int out_size, void* d_ws, size_t ws_size,
                              hipStream_t stream) {
    const float* lt = (const float*)d_in[0];
    const float* lp = (const float*)d_in[1];
    const float* lf = (const float*)d_in[2];
    const float* ht = (const float*)d_in[3];
    const float* hp = (const float*)d_in[4];
    const float* hf = (const float*)d_in[5];
    const float* W0 = (const float*)d_in[6];
    const float* b0 = (const float*)d_in[7];
    const float* g0 = (const float*)d_in[8];
    const float* be0 = (const float*)d_in[9];
    const float* W1 = (const float*)d_in[10];
    const float* b1 = (const float*)d_in[11];
    const float* g1 = (const float*)d_in[12];
    const float* be1 = (const float*)d_in[13];

    char* ws = (char*)d_ws;
    u16* y0 = (u16*)ws;                         // 16.78 MB (y0, then y1pre in place)
    u16* hT = (u16*)(ws + 16777216);            // 4.19 MB
    int* idx = (int*)(ws + 20971520);           // 256 KB
    float* gstat = (float*)(ws + 21233664);     // 2 KB: [0:256]=L0 stats, [256:512]=L1
    u16* W0b = (u16*)(ws + 21235712);           // 48 KB
    u16* W1b = (u16*)(ws + 21284864);           // 32 KB
    float* gpart = (float*)(ws + 21317632);     // 1 MB per-block stat partials (reused)

    k_prep_w<<<96, 256, 0, stream>>>(W0, W1, W0b, W1b);
    k_prep_h<<<dim3(8, 32, 2), 256, 0, stream>>>(hf, hT);
    k_argmin<<<2048, 256, 0, stream>>>(lt, lp, ht, hp, idx);
    k_l0<<<1024, 256, 0, stream>>>(lf, hT, idx, W0b, b0, y0, gpart);
    k_red<<<256, 256, 0, stream>>>(gpart, gstat);
    k_l1<<<1024, 256, 0, stream>>>(y0, g0, be0, W1b, b1, gstat, gpart);
    k_red<<<256, 256, 0, stream>>>(gpart, gstat + 256);
    k_bn1<<<4096, 256, 0, stream>>>(y0, gstat, g1, be1, (float*)d_out);
}